// Round 8
// baseline (129.632 us; speedup 1.0000x reference)
//
#include <hip/hip_runtime.h>

#define POS_IN 63
#define HID 128
#define TOTAL 8789
#define NB 32
#define NPTS 65536

#define PB_OFF 8064
#define SW_OFF 8192
#define SB_OFF 8320
#define CW_OFF 8321
#define CB_OFF 8786

#define BLOCKS_PER_BATCH 32
#define PTS_PER_BLOCK (NPTS / BLOCKS_PER_BATCH) /* 2048 */
#define ITERS (PTS_PER_BLOCK / 256)             /* 8 */

typedef __attribute__((ext_vector_type(8))) short s16x8;
typedef __attribute__((ext_vector_type(4))) float f32x4;
typedef __bf16 bf16x2 __attribute__((ext_vector_type(2)));

// f32 -> bf16 RNE, integer path (setup only; proven R2)
__device__ __forceinline__ unsigned short f2bf(float v) {
    unsigned u = __builtin_bit_cast(unsigned, v);
    unsigned r = 0x7fffu + ((u >> 16) & 1u);
    return (unsigned short)((u + r) >> 16);
}
// hot-path pack: native __bf16 casts -> v_cvt_pk_bf16_f32 (proven R6/R7)
__device__ __forceinline__ unsigned pk2(float a, float b) {
    bf16x2 v;
    v[0] = (__bf16)a;
    v[1] = (__bf16)b;
    return __builtin_bit_cast(unsigned, v);
}

// __launch_bounds__(256) ONLY — no min-waves arg. (256,4) mis-executes
// (R3/R4); (256,2) may have side effects. Occupancy strategy: unified
// arch+AGPR <= 128 via half-acc split + wB2 moved to LDS.
__global__ __launch_bounds__(256) void nerf_mlp_kernel(
        const float* __restrict__ params,
        const float* __restrict__ points,
        const float* __restrict__ dirs,
        float* __restrict__ out)
{
    // LDS map: [0,32768) per-wave enc buffers (8KB each), aliased at start by
    // the pw bf16 stage ([128][72] ushort = 18432B).
    // [32768,36864) per-wave hbuf (1024B each, stride 64B rows).
    // [36864,37888) wb2: layer-2 weight frags [m][o<4][kg] 16B each.
    __shared__ __align__(16) unsigned char smem[37888];
    unsigned short* stage = (unsigned short*)smem;

    const int tid = threadIdx.x;
    const int lane = tid & 63;
    const int wid = tid >> 6;
    const int b = blockIdx.y;
    const float* P = params + (size_t)b * TOTAL;

    // ---- stage pw (128x63) as bf16, row stride 72; k=63 column = layer-1
    // bias (bias-in-K: e[63]=1.0). Proven R6/R7.
    for (int idx = tid; idx < 8064; idx += 256) {
        int n = idx / 63;
        int k = idx - n * 63;
        stage[n * 72 + k] = f2bf(P[idx]);
        if (k == 0) stage[n * 72 + 63] = f2bf(P[PB_OFF + n]);
    }
    __syncthreads();

    const int c = lane & 15;   // tile col: point-in-tile (and h low bits)
    const int kg = lane >> 4;  // k-group 0..3

    // ---- 16 persistent layer-1 fragments: lane holds pw[n=nt*16+c][k slice]
    s16x8 wB[8][2];
    #pragma unroll
    for (int nt = 0; nt < 8; ++nt) {
        #pragma unroll
        for (int kh = 0; kh < 2; ++kh) {
            int n = nt * 16 + c;
            int k = kh * 32 + kg * 8;
            uint4 raw = *(const uint4*)&stage[n * 72 + k];
            wB[nt][kh] = __builtin_bit_cast(s16x8, raw);
        }
    }

    // ---- layer-2 weight frags into LDS (1KB), written by wave 0 only.
    // Layout: wb2 + m*256 + o*64 + kg*16  (o = output row: 0..2 color, 3 sigma)
    unsigned char* wb2 = smem + 36864;
    if (wid == 0 && c < 4) {
        const int base = (c == 3) ? SW_OFF : (CW_OFF + c * 155);
        #pragma unroll
        for (int m = 0; m < 4; ++m) {
            const int h0 = m * 32 + kg * 8;
            uint4 dd;
            dd.x = pk2(P[base + h0 + 0], P[base + h0 + 1]);
            dd.y = pk2(P[base + h0 + 2], P[base + h0 + 3]);
            dd.z = pk2(P[base + h0 + 4], P[base + h0 + 5]);
            dd.w = pk2(P[base + h0 + 6], P[base + h0 + 7]);
            *(uint4*)(wb2 + m * 256 + c * 64 + kg * 16) = dd;
        }
    }
    __syncthreads();   // stage area -> enc buffers; wb2 visible to all waves

    const int ch = lane & 3;          // output channel this lane stores
    const float cbias = P[ch < 3 ? (CB_OFF + ch) : SB_OFF];

    unsigned char* encb = smem + wid * 8192;           // [kq][p][16B] bf16
    unsigned char* hbuf = smem + 32768 + wid * 1024;   // [16pt][64B] bounce

    const size_t bpts = (size_t)b * NPTS;
    const int n0b = blockIdx.x * PTS_PER_BLOCK;

    for (int it = 0; it < ITERS; ++it) {
        const int n0 = n0b + it * 256 + wid * 64;  // this wave's 64-pt chunk
        const int p = n0 + lane;

        const float* pp = points + (bpts + p) * 3;
        float x = pp[0], y = pp[1], z = pp[2];
        const float* dd = dirs + (bpts + p) * 3;
        float dx = dd[0], dy = dd[1], dz = dd[2];

        // ---- positional encoding (63 + bias slot), angle-doubling sincos
        float e[64];
        e[0] = x; e[1] = y; e[2] = z; e[63] = 1.0f;
        #pragma unroll
        for (int i = 0; i < 3; ++i) {
            float v = (i == 0) ? x : (i == 1) ? y : z;
            float s = __sinf(v), co = __cosf(v);
            e[3 + i * 10] = s; e[33 + i * 10] = co;
            #pragma unroll
            for (int f = 1; f < 10; ++f) {
                float ns = 2.f * s * co;
                float nc = 1.f - 2.f * s * s;
                s = ns; co = nc;
                e[3 + i * 10 + f] = s;
                e[33 + i * 10 + f] = co;
            }
        }

        // ---- dir encoding folded into per-point color partials (3 regs)
        float cp0 = 0.f, cp1 = 0.f, cp2 = 0.f;
        #pragma unroll
        for (int i = 0; i < 3; ++i) {
            float v = (i == 0) ? dx : (i == 1) ? dy : dz;
            cp0 = fmaf(v, P[CW_OFF + 128 + i], cp0);
            cp1 = fmaf(v, P[CW_OFF + 155 + 128 + i], cp1);
            cp2 = fmaf(v, P[CW_OFF + 310 + 128 + i], cp2);
            float s = __sinf(v), co = __cosf(v);
            #pragma unroll
            for (int f = 0; f < 4; ++f) {
                if (f > 0) {
                    float ns = 2.f * s * co;
                    float nc = 1.f - 2.f * s * s;
                    s = ns; co = nc;
                }
                int si = 128 + 3 + i * 4 + f;
                int ci = 128 + 15 + i * 4 + f;
                cp0 = fmaf(s, P[CW_OFF + si], cp0);
                cp1 = fmaf(s, P[CW_OFF + 155 + si], cp1);
                cp2 = fmaf(s, P[CW_OFF + 310 + si], cp2);
                cp0 = fmaf(co, P[CW_OFF + ci], cp0);
                cp1 = fmaf(co, P[CW_OFF + 155 + ci], cp1);
                cp2 = fmaf(co, P[CW_OFF + 310 + ci], cp2);
            }
        }

        // ---- pack enc to LDS (bf16), layout [kq][point][16B]
        #pragma unroll
        for (int kq = 0; kq < 8; ++kq) {
            uint4 q;
            q.x = pk2(e[kq * 8 + 0], e[kq * 8 + 1]);
            q.y = pk2(e[kq * 8 + 2], e[kq * 8 + 3]);
            q.z = pk2(e[kq * 8 + 4], e[kq * 8 + 5]);
            q.w = pk2(e[kq * 8 + 6], e[kq * 8 + 7]);
            *(uint4*)(encb + kq * 1024 + lane * 16) = q;
        }

        float* outp = out + (bpts + n0) * 4;

        // ---- 4 m-tiles of 16 points
        #pragma unroll
        for (int t = 0; t < 4; ++t) {
            uint4 a0r = *(const uint4*)(encb + kg * 1024 + (t * 16 + c) * 16);
            uint4 a1r = *(const uint4*)(encb + (4 + kg) * 1024 + (t * 16 + c) * 16);
            s16x8 A0 = __builtin_bit_cast(s16x8, a0r);
            s16x8 A1 = __builtin_bit_cast(s16x8, a1r);

            f32x4 acc2 = (f32x4){0.f, 0.f, 0.f, 0.f};

            // two nt-halves: peak live acc = 4 frags (16 AGPR) instead of 8
            #pragma unroll
            for (int half = 0; half < 2; ++half) {
                // SWAPPED layer-1: D[h][pt]; lane (c,kg) reg j holds
                // h = (half*4+nt)*16 + kg*4 + j, pt = t*16 + c
                f32x4 acc[4];
                #pragma unroll
                for (int nt = 0; nt < 4; ++nt) {
                    acc[nt] = (f32x4){0.f, 0.f, 0.f, 0.f};
                    acc[nt] = __builtin_amdgcn_mfma_f32_16x16x32_bf16(wB[half * 4 + nt][0], A0, acc[nt], 0, 0, 0);
                    acc[nt] = __builtin_amdgcn_mfma_f32_16x16x32_bf16(wB[half * 4 + nt][1], A1, acc[nt], 0, 0, 0);
                    #pragma unroll
                    for (int j = 0; j < 4; ++j)
                        acc[nt][j] = fmaxf(acc[nt][j], 0.f);   // relu(h+pb)
                }

                // layer-2 chunks m = half*2 + {0,1}: LDS transpose bounce,
                // row stride 64B (balanced read banks).
                #pragma unroll
                for (int lm = 0; lm < 2; ++lm) {
                    const int m = half * 2 + lm;
                    unsigned q0 = pk2(acc[2 * lm][0], acc[2 * lm][1]);
                    unsigned q1 = pk2(acc[2 * lm][2], acc[2 * lm][3]);
                    unsigned q2 = pk2(acc[2 * lm + 1][0], acc[2 * lm + 1][1]);
                    unsigned q3 = pk2(acc[2 * lm + 1][2], acc[2 * lm + 1][3]);
                    *(uint2*)(hbuf + c * 64 + kg * 8)      = make_uint2(q0, q1);
                    *(uint2*)(hbuf + c * 64 + 32 + kg * 8) = make_uint2(q2, q3);
                    // A2 frag: row=pt(c), k-slice kg*8..+8 (same-wave DS
                    // write->read is in-order; proven R7)
                    uint4 ar = *(const uint4*)(hbuf + c * 64 + kg * 16);
                    s16x8 A2 = __builtin_bit_cast(s16x8, ar);
                    // B2 frag from LDS; cols o>=4 are zero (exec-masked read)
                    s16x8 B2 = (s16x8){0, 0, 0, 0, 0, 0, 0, 0};
                    if (c < 4) {
                        uint4 br = *(const uint4*)(wb2 + m * 256 + c * 64 + kg * 16);
                        B2 = __builtin_bit_cast(s16x8, br);
                    }
                    acc2 = __builtin_amdgcn_mfma_f32_16x16x32_bf16(A2, B2, acc2, 0, 0, 0);
                }
            }

            // D2: lane (c,kg) reg j = out(pt=t*16+kg*4+j, o=c), valid c<4.
            // Bounce through hbuf floats for coalesced stores.
            if (c < 4) {
                #pragma unroll
                for (int j = 0; j < 4; ++j)
                    ((float*)hbuf)[(kg * 4 + j) * 4 + c] = acc2[j];
            }
            float v = ((float*)hbuf)[lane];

            // color partial of this lane's point (held by lane t*16+pt)
            int src = t * 16 + (lane >> 2);
            float p0 = __shfl(cp0, src, 64);
            float p1 = __shfl(cp1, src, 64);
            float p2 = __shfl(cp2, src, 64);
            float cpv = (ch == 0) ? p0 : (ch == 1) ? p1 : (ch == 2) ? p2 : 0.f;

            v += cpv + cbias;
            float sig = 1.f / (1.f + __expf(-v));
            v = (ch < 3) ? sig : v;             // sigmoid on color only

            outp[t * 64 + lane] = v;            // coalesced: offset = t*64+lane
        }
    }
}

extern "C" void kernel_launch(void* const* d_in, const int* in_sizes, int n_in,
                              void* d_out, int out_size, void* d_ws, size_t ws_size,
                              hipStream_t stream) {
    const float* params = (const float*)d_in[0];
    const float* points = (const float*)d_in[1];
    const float* dirs   = (const float*)d_in[2];
    float* out = (float*)d_out;
    dim3 grid(BLOCKS_PER_BATCH, NB);
    nerf_mlp_kernel<<<grid, 256, 0, stream>>>(params, points, dirs, out);
}

// Round 9
// 102.059 us; speedup vs baseline: 1.2702x; 1.2702x over previous
//
#include <hip/hip_runtime.h>

#define POS_IN 63
#define HID 128
#define TOTAL 8789
#define NB 32
#define NPTS 65536

#define PB_OFF 8064
#define SW_OFF 8192
#define SB_OFF 8320
#define CW_OFF 8321
#define CB_OFF 8786

#define BLOCKS_PER_BATCH 16
#define PTS_PER_BLOCK (NPTS / BLOCKS_PER_BATCH) /* 4096 */
#define ITERS (PTS_PER_BLOCK / 256)             /* 16 */

/* hbuf strides: chosen for 8B alignment AND bank spread.
   c-stride 72B (18 dw): 18c mod 32 -> 16 distinct banks over c.
   kg-stride 1160B (290 dw): 290 mod 32 = 2 -> kg adds {0,2,4,6}.
   Writes/reads are b64: ~2-way worst case (free per m136). */
#define HB_CS 72
#define HB_KS 1160
#define HB_WAVE 4640  /* 4*HB_KS */

typedef __attribute__((ext_vector_type(8))) short s16x8;
typedef __attribute__((ext_vector_type(4))) float f32x4;
typedef __bf16 bf16x2 __attribute__((ext_vector_type(2)));

// f32 -> bf16 RNE, integer path (setup only; proven R2)
__device__ __forceinline__ unsigned short f2bf(float v) {
    unsigned u = __builtin_bit_cast(unsigned, v);
    unsigned r = 0x7fffu + ((u >> 16) & 1u);
    return (unsigned short)((u + r) >> 16);
}
// hot-path pack: native __bf16 casts -> v_cvt_pk_bf16_f32 (proven R6/R7)
__device__ __forceinline__ unsigned pk2(float a, float b) {
    bf16x2 v;
    v[0] = (__bf16)a;
    v[1] = (__bf16)b;
    return __builtin_bit_cast(unsigned, v);
}

// __launch_bounds__(256) only — (256,4) mis-executes (R3/R4).
__global__ __launch_bounds__(256) void nerf_mlp_kernel(
        const float* __restrict__ params,
        const float* __restrict__ points,
        const float* __restrict__ dirs,
        float* __restrict__ out)
{
    // LDS map: [0,32768) per-wave enc buffers (8KB each), aliased at start by
    // the pw bf16 stage ([128][72] ushort = 18432B).
    // [32768, 32768+4*4640) per-wave hbuf (layer-2 bounce, bank-spread).
    // [51328, 52352) wb2: layer-2 weight frags.
    __shared__ __align__(16) unsigned char smem[52352];
    unsigned short* stage = (unsigned short*)smem;

    const int tid = threadIdx.x;
    const int lane = tid & 63;
    const int wid = tid >> 6;
    const int b = blockIdx.y;
    const float* P = params + (size_t)b * TOTAL;

    // ---- stage pw (128x63) as bf16, row stride 72; k=63 column = layer-1
    // bias (bias-in-K: e[63]=1.0). Proven R6/R7.
    for (int idx = tid; idx < 8064; idx += 256) {
        int n = idx / 63;
        int k = idx - n * 63;
        stage[n * 72 + k] = f2bf(P[idx]);
        if (k == 0) stage[n * 72 + 63] = f2bf(P[PB_OFF + n]);
    }
    __syncthreads();

    const int c = lane & 15;   // tile col: point-in-tile (and h low bits)
    const int kg = lane >> 4;  // k-group 0..3

    // ---- 16 persistent layer-1 fragments: lane holds pw[n=nt*16+c][k slice]
    s16x8 wB[8][2];
    #pragma unroll
    for (int nt = 0; nt < 8; ++nt) {
        #pragma unroll
        for (int kh = 0; kh < 2; ++kh) {
            int n = nt * 16 + c;
            int k = kh * 32 + kg * 8;
            uint4 raw = *(const uint4*)&stage[n * 72 + k];
            wB[nt][kh] = __builtin_bit_cast(s16x8, raw);
        }
    }

    // ---- layer-2 weight frags into LDS (1KB), written by wave 0 only.
    // Layout: wb2 + m*256 + o*64 + kg*16  (o: 0..2 color rows, 3 sigma row)
    unsigned char* wb2 = smem + 51328;
    if (wid == 0 && c < 4) {
        const int base = (c == 3) ? SW_OFF : (CW_OFF + c * 155);
        #pragma unroll
        for (int m = 0; m < 4; ++m) {
            const int h0 = m * 32 + kg * 8;
            uint4 dd;
            dd.x = pk2(P[base + h0 + 0], P[base + h0 + 1]);
            dd.y = pk2(P[base + h0 + 2], P[base + h0 + 3]);
            dd.z = pk2(P[base + h0 + 4], P[base + h0 + 5]);
            dd.w = pk2(P[base + h0 + 6], P[base + h0 + 7]);
            *(uint4*)(wb2 + m * 256 + c * 64 + kg * 16) = dd;
        }
    }
    __syncthreads();   // stage area -> enc buffers; wb2 visible to all waves

    const int ch = lane & 3;          // output channel this lane stores
    const float cbias = P[ch < 3 ? (CB_OFF + ch) : SB_OFF];

    unsigned char* encb = smem + wid * 8192;              // [kq][p][16B] bf16
    unsigned char* hbuf = smem + 32768 + wid * HB_WAVE;   // bounce buffer

    const size_t bpts = (size_t)b * NPTS;
    const int n0b = blockIdx.x * PTS_PER_BLOCK;

    for (int it = 0; it < ITERS; ++it) {
        const int n0 = n0b + it * 256 + wid * 64;  // this wave's 64-pt chunk
        const int p = n0 + lane;

        const float* pp = points + (bpts + p) * 3;
        float x = pp[0], y = pp[1], z = pp[2];
        const float* dd = dirs + (bpts + p) * 3;
        float dx = dd[0], dy = dd[1], dz = dd[2];

        // ---- positional encoding (63 + bias slot), angle-doubling sincos
        float e[64];
        e[0] = x; e[1] = y; e[2] = z; e[63] = 1.0f;
        #pragma unroll
        for (int i = 0; i < 3; ++i) {
            float v = (i == 0) ? x : (i == 1) ? y : z;
            float s = __sinf(v), co = __cosf(v);
            e[3 + i * 10] = s; e[33 + i * 10] = co;
            #pragma unroll
            for (int f = 1; f < 10; ++f) {
                float ns = 2.f * s * co;
                float nc = 1.f - 2.f * s * s;
                s = ns; co = nc;
                e[3 + i * 10 + f] = s;
                e[33 + i * 10 + f] = co;
            }
        }

        // ---- dir encoding folded into per-point color partials (3 regs)
        float cp0 = 0.f, cp1 = 0.f, cp2 = 0.f;
        #pragma unroll
        for (int i = 0; i < 3; ++i) {
            float v = (i == 0) ? dx : (i == 1) ? dy : dz;
            cp0 = fmaf(v, P[CW_OFF + 128 + i], cp0);
            cp1 = fmaf(v, P[CW_OFF + 155 + 128 + i], cp1);
            cp2 = fmaf(v, P[CW_OFF + 310 + 128 + i], cp2);
            float s = __sinf(v), co = __cosf(v);
            #pragma unroll
            for (int f = 0; f < 4; ++f) {
                if (f > 0) {
                    float ns = 2.f * s * co;
                    float nc = 1.f - 2.f * s * s;
                    s = ns; co = nc;
                }
                int si = 128 + 3 + i * 4 + f;
                int ci = 128 + 15 + i * 4 + f;
                cp0 = fmaf(s, P[CW_OFF + si], cp0);
                cp1 = fmaf(s, P[CW_OFF + 155 + si], cp1);
                cp2 = fmaf(s, P[CW_OFF + 310 + si], cp2);
                cp0 = fmaf(co, P[CW_OFF + ci], cp0);
                cp1 = fmaf(co, P[CW_OFF + 155 + ci], cp1);
                cp2 = fmaf(co, P[CW_OFF + 310 + ci], cp2);
            }
        }

        // ---- pack enc to LDS (bf16), layout [kq][point][16B]
        #pragma unroll
        for (int kq = 0; kq < 8; ++kq) {
            uint4 q;
            q.x = pk2(e[kq * 8 + 0], e[kq * 8 + 1]);
            q.y = pk2(e[kq * 8 + 2], e[kq * 8 + 3]);
            q.z = pk2(e[kq * 8 + 4], e[kq * 8 + 5]);
            q.w = pk2(e[kq * 8 + 6], e[kq * 8 + 7]);
            *(uint4*)(encb + kq * 1024 + lane * 16) = q;
        }

        float* outp = out + (bpts + n0) * 4;

        // ---- 4 m-tiles of 16 points
        #pragma unroll
        for (int t = 0; t < 4; ++t) {
            uint4 a0r = *(const uint4*)(encb + kg * 1024 + (t * 16 + c) * 16);
            uint4 a1r = *(const uint4*)(encb + (4 + kg) * 1024 + (t * 16 + c) * 16);
            s16x8 A0 = __builtin_bit_cast(s16x8, a0r);
            s16x8 A1 = __builtin_bit_cast(s16x8, a1r);

            f32x4 acc2 = (f32x4){0.f, 0.f, 0.f, 0.f};

            // two nt-halves: peak live acc = 4 frags instead of 8
            #pragma unroll
            for (int half = 0; half < 2; ++half) {
                // SWAPPED layer-1: D[h][pt]; lane (c,kg) reg j holds
                // h = (half*4+nt)*16 + kg*4 + j, pt = t*16 + c
                f32x4 acc[4];
                #pragma unroll
                for (int nt = 0; nt < 4; ++nt) {
                    acc[nt] = (f32x4){0.f, 0.f, 0.f, 0.f};
                    acc[nt] = __builtin_amdgcn_mfma_f32_16x16x32_bf16(wB[half * 4 + nt][0], A0, acc[nt], 0, 0, 0);
                    acc[nt] = __builtin_amdgcn_mfma_f32_16x16x32_bf16(wB[half * 4 + nt][1], A1, acc[nt], 0, 0, 0);
                    #pragma unroll
                    for (int j = 0; j < 4; ++j)
                        acc[nt][j] = fmaxf(acc[nt][j], 0.f);   // relu(h+pb)
                }

                // layer-2 chunks m = half*2 + {0,1}: bank-spread LDS bounce.
                // Lane (c,kg) holds dwords [p(nt0,j01), p(nt0,j23),
                //                           p(nt1,j01), p(nt1,j23)].
                // A2 elem e needs h_loc = kg*8+e: dword w from lane
                // (c, kg_s=2(kg&1)+(w>>1)), dword idx nt_s*2+(w&1), nt_s=kg>>1.
                #pragma unroll
                for (int lm = 0; lm < 2; ++lm) {
                    const int m = half * 2 + lm;
                    unsigned q0 = pk2(acc[2 * lm][0], acc[2 * lm][1]);
                    unsigned q1 = pk2(acc[2 * lm][2], acc[2 * lm][3]);
                    unsigned q2 = pk2(acc[2 * lm + 1][0], acc[2 * lm + 1][1]);
                    unsigned q3 = pk2(acc[2 * lm + 1][2], acc[2 * lm + 1][3]);
                    *(uint2*)(hbuf + kg * HB_KS + c * HB_CS)     = make_uint2(q0, q1);
                    *(uint2*)(hbuf + kg * HB_KS + c * HB_CS + 8) = make_uint2(q2, q3);
                    // same-wave DS write->read is in-order (proven R7/R8)
                    const int nt_off = (kg >> 1) * 8;   // byte offset: nt_s*2 dwords
                    uint2 lo2 = *(const uint2*)(hbuf + (2 * (kg & 1)) * HB_KS + c * HB_CS + nt_off);
                    uint2 hi2 = *(const uint2*)(hbuf + (2 * (kg & 1) + 1) * HB_KS + c * HB_CS + nt_off);
                    uint4 ar = make_uint4(lo2.x, lo2.y, hi2.x, hi2.y);
                    s16x8 A2 = __builtin_bit_cast(s16x8, ar);
                    // B2 frag from LDS; cols o>=4 zero (exec-masked read)
                    s16x8 B2 = (s16x8){0, 0, 0, 0, 0, 0, 0, 0};
                    if (c < 4) {
                        uint4 br = *(const uint4*)(wb2 + m * 256 + c * 64 + kg * 16);
                        B2 = __builtin_bit_cast(s16x8, br);
                    }
                    acc2 = __builtin_amdgcn_mfma_f32_16x16x32_bf16(A2, B2, acc2, 0, 0, 0);
                }
            }

            // D2: lane (c,kg) reg j = out(pt=t*16+kg*4+j, o=c), valid c<4.
            // Bounce via hbuf, 17-dword row stride (bank-spread, b32 ops).
            if (c < 4) {
                #pragma unroll
                for (int j = 0; j < 4; ++j)
                    *(float*)(hbuf + ((kg * 4 + j) * 17 + c) * 4) = acc2[j];
            }
            float v = *(const float*)(hbuf + ((lane >> 2) * 17 + (lane & 3)) * 4);

            // color partial of this lane's point (held by lane t*16+pt)
            int src = t * 16 + (lane >> 2);
            float p0 = __shfl(cp0, src, 64);
            float p1 = __shfl(cp1, src, 64);
            float p2 = __shfl(cp2, src, 64);
            float cpv = (ch == 0) ? p0 : (ch == 1) ? p1 : (ch == 2) ? p2 : 0.f;

            v += cpv + cbias;
            float sig = 1.f / (1.f + __expf(-v));
            v = (ch < 3) ? sig : v;             // sigmoid on color only

            outp[t * 64 + lane] = v;            // coalesced: offset = t*64+lane
        }
    }
}

extern "C" void kernel_launch(void* const* d_in, const int* in_sizes, int n_in,
                              void* d_out, int out_size, void* d_ws, size_t ws_size,
                              hipStream_t stream) {
    const float* params = (const float*)d_in[0];
    const float* points = (const float*)d_in[1];
    const float* dirs   = (const float*)d_in[2];
    float* out = (float*)d_out;
    dim3 grid(BLOCKS_PER_BATCH, NB);
    nerf_mlp_kernel<<<grid, 256, 0, stream>>>(params, points, dirs, out);
}

// Round 10
// 98.294 us; speedup vs baseline: 1.3188x; 1.0383x over previous
//
#include <hip/hip_runtime.h>

#define POS_IN 63
#define HID 128
#define TOTAL 8789
#define NB 32
#define NPTS 65536

#define PB_OFF 8064
#define SW_OFF 8192
#define SB_OFF 8320
#define CW_OFF 8321
#define CB_OFF 8786

#define BLOCKS_PER_BATCH 16
#define PTS_PER_BLOCK (NPTS / BLOCKS_PER_BATCH) /* 4096 */
#define ITERS (PTS_PER_BLOCK / 256)             /* 16 */

typedef __attribute__((ext_vector_type(8))) short s16x8;
typedef __attribute__((ext_vector_type(4))) float f32x4;
typedef __bf16 bf16x2 __attribute__((ext_vector_type(2)));

// f32 -> bf16 RNE, integer path (setup only; proven R2)
__device__ __forceinline__ unsigned short f2bf(float v) {
    unsigned u = __builtin_bit_cast(unsigned, v);
    unsigned r = 0x7fffu + ((u >> 16) & 1u);
    return (unsigned short)((u + r) >> 16);
}
// hot-path pack: native __bf16 casts -> v_cvt_pk_bf16_f32 (proven R6-R9)
__device__ __forceinline__ unsigned pk2(float a, float b) {
    bf16x2 v;
    v[0] = (__bf16)a;
    v[1] = (__bf16)b;
    return __builtin_bit_cast(unsigned, v);
}

// __launch_bounds__(256) only — (256,4) mis-executes (R3/R4).
__global__ __launch_bounds__(256) void nerf_mlp_kernel(
        const float* __restrict__ params,
        const float* __restrict__ points,
        const float* __restrict__ dirs,
        float* __restrict__ out)
{
    // LDS: [0,32768) per-wave enc bufs (8KB), aliased at start by pw stage
    // ([128][72] ushort = 18432B). [32768,49152) per-wave dir bufs (4KB).
    __shared__ __align__(16) unsigned char smem[49152];
    unsigned short* stage = (unsigned short*)smem;

    const int tid = threadIdx.x;
    const int lane = tid & 63;
    const int wid = tid >> 6;
    const int b = blockIdx.y;
    const float* P = params + (size_t)b * TOTAL;

    // ---- stage pw (128x63) as bf16, row stride 72; k=63 column = layer-1
    // bias (bias-in-K: e[63]=1.0). Proven R6-R9.
    for (int idx = tid; idx < 8064; idx += 256) {
        int n = idx / 63;
        int k = idx - n * 63;
        stage[n * 72 + k] = f2bf(P[idx]);
        if (k == 0) stage[n * 72 + 63] = f2bf(P[PB_OFF + n]);
    }
    __syncthreads();

    const int c = lane & 15;   // tile col: point-in-tile (and o for layer-2)
    const int kg = lane >> 4;  // k-group 0..3

    // ---- 16 persistent layer-1 fragments: lane holds pw[n=nt*16+c][k slice]
    s16x8 wB[8][2];
    #pragma unroll
    for (int nt = 0; nt < 8; ++nt) {
        #pragma unroll
        for (int kh = 0; kh < 2; ++kh) {
            int n = nt * 16 + c;
            int k = kh * 32 + kg * 8;
            uint4 raw = *(const uint4*)&stage[n * 72 + k];
            wB[nt][kh] = __builtin_bit_cast(s16x8, raw);
        }
    }

    // ---- layer-2 h-chunk B frags (16 VGPR), PERMUTED to match A2's local
    // packing: physical slot (kg,e) holds logical h = (e<4 ? 2m : 2m+1)*16
    // + kg*4 + (e&3). MFMA sums over physical slots, so any bijection works
    // as long as A and B agree — this one makes A2 = pk2(acc) with NO
    // cross-lane movement. o = c: 0..2 color rows, 3 sigma row, >=4 zero.
    s16x8 wB2h[4];
    #pragma unroll
    for (int m = 0; m < 4; ++m) {
        uint4 dd = make_uint4(0u, 0u, 0u, 0u);
        if (c < 4) {
            const int base = (c == 3) ? SW_OFF : (CW_OFF + c * 155);
            const int b0 = base + 32 * m + kg * 4;
            dd.x = pk2(P[b0 + 0],  P[b0 + 1]);
            dd.y = pk2(P[b0 + 2],  P[b0 + 3]);
            dd.z = pk2(P[b0 + 16], P[b0 + 17]);
            dd.w = pk2(P[b0 + 18], P[b0 + 19]);
        }
        wB2h[m] = __builtin_bit_cast(s16x8, dd);
    }
    // ---- dir+bias chunk B frag (4 VGPR): k_loc = kg*8+e; k_loc<27 -> dir
    // weights cw[o][128+k_loc] (zero for sigma row), k_loc==27 -> bias
    // (cb[o] / sb), else 0.  A2d slot 27 carries 1.0.
    s16x8 wB2d;
    {
        float vals[8];
        #pragma unroll
        for (int e = 0; e < 8; ++e) {
            int k_loc = kg * 8 + e;
            float v = 0.f;
            if (c < 3) {
                if (k_loc < 27)       v = P[CW_OFF + c * 155 + 128 + k_loc];
                else if (k_loc == 27) v = P[CB_OFF + c];
            } else if (c == 3) {
                if (k_loc == 27)      v = P[SB_OFF];
            }
            vals[e] = v;
        }
        uint4 dd;
        dd.x = pk2(vals[0], vals[1]);
        dd.y = pk2(vals[2], vals[3]);
        dd.z = pk2(vals[4], vals[5]);
        dd.w = pk2(vals[6], vals[7]);
        wB2d = __builtin_bit_cast(s16x8, dd);
    }
    __syncthreads();   // stage area -> enc buffers

    unsigned char* encb = smem + wid * 8192;            // [kq][pt][16B]
    unsigned char* dirb = smem + 32768 + wid * 4096;    // [kq2][pt][16B]

    const size_t bpts = (size_t)b * NPTS;
    const int n0b = blockIdx.x * PTS_PER_BLOCK;

    for (int it = 0; it < ITERS; ++it) {
        const int n0 = n0b + it * 256 + wid * 64;  // this wave's 64-pt chunk
        const int p = n0 + lane;

        const float* pp = points + (bpts + p) * 3;
        float x = pp[0], y = pp[1], z = pp[2];
        const float* dd = dirs + (bpts + p) * 3;
        float dx = dd[0], dy = dd[1], dz = dd[2];

        // ---- dir encoding -> d[32]: [dx,dy,dz, sin(i,f), cos(i,f), 1.0, 0x4]
        float d[32];
        d[0] = dx; d[1] = dy; d[2] = dz;
        d[27] = 1.0f; d[28] = 0.f; d[29] = 0.f; d[30] = 0.f; d[31] = 0.f;
        #pragma unroll
        for (int i = 0; i < 3; ++i) {
            float v = (i == 0) ? dx : (i == 1) ? dy : dz;
            float s = __sinf(v), co = __cosf(v);
            d[3 + i * 4] = s; d[15 + i * 4] = co;
            #pragma unroll
            for (int f = 1; f < 4; ++f) {
                float ns = 2.f * s * co;
                float nc = 1.f - 2.f * s * s;
                s = ns; co = nc;
                d[3 + i * 4 + f] = s;
                d[15 + i * 4 + f] = co;
            }
        }
        // pack dir enc to LDS, layout [kq2][pt][8 bf16]
        #pragma unroll
        for (int kq = 0; kq < 4; ++kq) {
            uint4 q;
            q.x = pk2(d[kq * 8 + 0], d[kq * 8 + 1]);
            q.y = pk2(d[kq * 8 + 2], d[kq * 8 + 3]);
            q.z = pk2(d[kq * 8 + 4], d[kq * 8 + 5]);
            q.w = pk2(d[kq * 8 + 6], d[kq * 8 + 7]);
            *(uint4*)(dirb + kq * 1024 + lane * 16) = q;
        }

        // ---- positional encoding (63 + bias slot), angle-doubling sincos
        float e[64];
        e[0] = x; e[1] = y; e[2] = z; e[63] = 1.0f;
        #pragma unroll
        for (int i = 0; i < 3; ++i) {
            float v = (i == 0) ? x : (i == 1) ? y : z;
            float s = __sinf(v), co = __cosf(v);
            e[3 + i * 10] = s; e[33 + i * 10] = co;
            #pragma unroll
            for (int f = 1; f < 10; ++f) {
                float ns = 2.f * s * co;
                float nc = 1.f - 2.f * s * s;
                s = ns; co = nc;
                e[3 + i * 10 + f] = s;
                e[33 + i * 10 + f] = co;
            }
        }
        #pragma unroll
        for (int kq = 0; kq < 8; ++kq) {
            uint4 q;
            q.x = pk2(e[kq * 8 + 0], e[kq * 8 + 1]);
            q.y = pk2(e[kq * 8 + 2], e[kq * 8 + 3]);
            q.z = pk2(e[kq * 8 + 4], e[kq * 8 + 5]);
            q.w = pk2(e[kq * 8 + 6], e[kq * 8 + 7]);
            *(uint4*)(encb + kq * 1024 + lane * 16) = q;
        }

        float* outp = out + (bpts + n0) * 4;

        // ---- 4 m-tiles of 16 points
        #pragma unroll
        for (int t = 0; t < 4; ++t) {
            uint4 a0r = *(const uint4*)(encb + kg * 1024 + (t * 16 + c) * 16);
            uint4 a1r = *(const uint4*)(encb + (4 + kg) * 1024 + (t * 16 + c) * 16);
            s16x8 A0 = __builtin_bit_cast(s16x8, a0r);
            s16x8 A1 = __builtin_bit_cast(s16x8, a1r);

            // dir+bias chunk of layer-2 (independent of layer-1)
            uint4 adr = *(const uint4*)(dirb + kg * 1024 + (t * 16 + c) * 16);
            s16x8 A2d = __builtin_bit_cast(s16x8, adr);
            f32x4 acc2 = (f32x4){0.f, 0.f, 0.f, 0.f};
            acc2 = __builtin_amdgcn_mfma_f32_16x16x32_bf16(A2d, wB2d, acc2, 0, 0, 0);

            // layer-1 (swapped: D[h][pt], pt = t*16+c on lane&15) fused with
            // layer-2 h-chunks: A2 = local pk2 of acc pair (permuted-B trick)
            #pragma unroll
            for (int m = 0; m < 4; ++m) {
                f32x4 accA = (f32x4){0.f, 0.f, 0.f, 0.f};
                f32x4 accB = (f32x4){0.f, 0.f, 0.f, 0.f};
                accA = __builtin_amdgcn_mfma_f32_16x16x32_bf16(wB[2 * m][0], A0, accA, 0, 0, 0);
                accA = __builtin_amdgcn_mfma_f32_16x16x32_bf16(wB[2 * m][1], A1, accA, 0, 0, 0);
                accB = __builtin_amdgcn_mfma_f32_16x16x32_bf16(wB[2 * m + 1][0], A0, accB, 0, 0, 0);
                accB = __builtin_amdgcn_mfma_f32_16x16x32_bf16(wB[2 * m + 1][1], A1, accB, 0, 0, 0);
                uint4 dd2;
                dd2.x = pk2(fmaxf(accA[0], 0.f), fmaxf(accA[1], 0.f));
                dd2.y = pk2(fmaxf(accA[2], 0.f), fmaxf(accA[3], 0.f));
                dd2.z = pk2(fmaxf(accB[0], 0.f), fmaxf(accB[1], 0.f));
                dd2.w = pk2(fmaxf(accB[2], 0.f), fmaxf(accB[3], 0.f));
                s16x8 A2 = __builtin_bit_cast(s16x8, dd2);
                acc2 = __builtin_amdgcn_mfma_f32_16x16x32_bf16(A2, wB2h[m], acc2, 0, 0, 0);
            }

            // D2: lane (c,kg) reg j = (pt = t*16+kg*4+j, o = c), valid c<4.
            // Direct stores: 4x dword from 16 lanes; L2 write-combines.
            if (c < 4) {
                #pragma unroll
                for (int j = 0; j < 4; ++j) {
                    float v = acc2[j];
                    float sig = 1.f / (1.f + __expf(-v));
                    v = (c < 3) ? sig : v;      // sigmoid on color only
                    outp[t * 64 + kg * 16 + j * 4 + c] = v;
                }
            }
        }
    }
}

extern "C" void kernel_launch(void* const* d_in, const int* in_sizes, int n_in,
                              void* d_out, int out_size, void* d_ws, size_t ws_size,
                              hipStream_t stream) {
    const float* params = (const float*)d_in[0];
    const float* points = (const float*)d_in[1];
    const float* dirs   = (const float*)d_in[2];
    float* out = (float*)d_out;
    dim3 grid(BLOCKS_PER_BATCH, NB);
    nerf_mlp_kernel<<<grid, 256, 0, stream>>>(params, points, dirs, out);
}